// Round 1
// baseline (544.348 us; speedup 1.0000x reference)
//
#include <hip/hip_runtime.h>
#include <hip/hip_bf16.h>

typedef __attribute__((ext_vector_type(8))) short short8;
typedef __attribute__((ext_vector_type(4))) float f32x4;
typedef __attribute__((ext_vector_type(4))) int i32x4;

#define LDS_BUF 40960      // bytes per buffer half: A(8KB) + B(32KB)
#define A_OFF 0
#define B_OFF 8192

// Grid: 4096 blocks = 512 MLPs x 8 m-tiles. Block: 512 threads (8 waves, 2M x 4N).
// Per block: computes h-pre[128 x 512] for one MLP k via bf16 MFMA, then fused
// relu + dot(W2) + b2 epilogue -> out[128 rows, k].
__global__ __launch_bounds__(512, 2)
void ens_mlp_kernel(const float* __restrict__ X,
                    const float* __restrict__ W1,
                    const float* __restrict__ B1,
                    const float* __restrict__ W2,
                    const float* __restrict__ B2,
                    float* __restrict__ out)
{
    extern __shared__ char smem[];
    const int t    = threadIdx.x;
    const int lane = t & 63;
    const int wv   = t >> 6;
    const int wm   = wv >> 2;   // 0..1  (M wave index)
    const int wn   = wv & 3;    // 0..3  (N wave index)

    // XCD-aware decode: 8 m-blocks of the same k land adjacent on one XCD.
    const int bb  = blockIdx.x;
    const int xcd = bb & 7;
    const int j   = bb >> 3;
    const int km  = xcd * 64 + (j >> 3);  // MLP index 0..511
    const int mt  = j & 7;                // m-tile 0..7

    const float* __restrict__ W1k = W1 + (size_t)km * (512 * 512);
    const float* __restrict__ Xm  = X + (size_t)mt * 128 * 512;

    f32x4 acc[4][8];
#pragma unroll
    for (int i = 0; i < 4; ++i)
#pragma unroll
        for (int p = 0; p < 8; ++p)
            acc[i][p] = (f32x4)0.0f;

    f32x4 sl[5][2];   // staged fp32 (8 floats per task)

    // Staging tasks (5 per thread per K-step):
    //  it<4 : W1 rows — id = it*512+t -> row=id>>2 (0..511), chunk c=id&3 (8 k's)
    //  it==4: X rows  — row=t>>2 (0..127), c=t&3
    // LDS dest is fragment-order: granule (c<<4)|(row&15) inside frag row>>4.
    auto stage_load = [&](int ks) {
#pragma unroll
        for (int it = 0; it < 5; ++it) {
            const float* src;
            if (it < 4) {
                int id  = it * 512 + t;
                int row = id >> 2, c = id & 3;
                src = W1k + row * 512 + ks * 32 + c * 8;
            } else {
                int row = t >> 2, c = t & 3;
                src = Xm + row * 512 + ks * 32 + c * 8;
            }
            sl[it][0] = *(const f32x4*)src;
            sl[it][1] = *(const f32x4*)(src + 4);
        }
    };

    auto stage_write = [&](int buf) {
        char* base = smem + buf * LDS_BUF;
#pragma unroll
        for (int it = 0; it < 5; ++it) {
            char* dst;
            if (it < 4) {
                int id  = it * 512 + t;
                int row = id >> 2, c = id & 3;
                dst = base + B_OFF + ((row >> 4) << 10) + (((c << 4) | (row & 15)) << 4);
            } else {
                int row = t >> 2, c = t & 3;
                dst = base + A_OFF + ((row >> 4) << 10) + (((c << 4) | (row & 15)) << 4);
            }
            union { __hip_bfloat162 h[4]; i32x4 v; } u;
            u.h[0] = __float22bfloat162_rn(make_float2(sl[it][0][0], sl[it][0][1]));
            u.h[1] = __float22bfloat162_rn(make_float2(sl[it][0][2], sl[it][0][3]));
            u.h[2] = __float22bfloat162_rn(make_float2(sl[it][1][0], sl[it][1][1]));
            u.h[3] = __float22bfloat162_rn(make_float2(sl[it][1][2], sl[it][1][3]));
            *(i32x4*)dst = u.v;
        }
    };

    // Fragment reads are linear (base + frag*1024 + lane*16): conflict-free.
    auto compute = [&](int buf) {
        const char* base = smem + buf * LDS_BUF;
        short8 av[4];
        short8 bv[8];
#pragma unroll
        for (int i = 0; i < 4; ++i)
            av[i] = *(const short8*)(base + A_OFF + ((wm * 4 + i) << 10) + (lane << 4));
#pragma unroll
        for (int p = 0; p < 8; ++p)
            bv[p] = *(const short8*)(base + B_OFF + ((wn * 8 + p) << 10) + (lane << 4));
#pragma unroll
        for (int i = 0; i < 4; ++i)
#pragma unroll
            for (int p = 0; p < 8; ++p)
                acc[i][p] = __builtin_amdgcn_mfma_f32_16x16x32_bf16(av[i], bv[p], acc[i][p], 0, 0, 0);
    };

    stage_load(0);
    stage_write(0);
    __syncthreads();

#pragma unroll 2
    for (int ks = 0; ks < 16; ++ks) {
        if (ks < 15) stage_load(ks + 1);      // issue global loads early (T14)
        compute(ks & 1);                      // ds_read + MFMA under load latency
        if (ks < 15) stage_write((ks + 1) & 1); // cvt + ds_write to other buffer
        __syncthreads();
    }

    // ---- fused epilogue: out[b, km] = sum_n relu(h + b1[n]) * w2[n] + b2 ----
    float b1v[8], w2v[8];
    const int nc = lane & 15;
#pragma unroll
    for (int p = 0; p < 8; ++p) {
        int n = wn * 128 + p * 16 + nc;
        b1v[p] = B1[km * 512 + n];
        w2v[p] = W2[km * 512 + n];
    }

    float part[4][4];
#pragma unroll
    for (int i = 0; i < 4; ++i)
#pragma unroll
        for (int r = 0; r < 4; ++r) {
            float s = 0.f;
#pragma unroll
            for (int p = 0; p < 8; ++p) {
                float h = acc[i][p][r] + b1v[p];
                h = h > 0.f ? h : 0.f;
                s += h * w2v[p];
            }
            // reduce over the 16 lanes that hold different n columns
#pragma unroll
            for (int d = 1; d < 16; d <<= 1)
                s += __shfl_xor(s, d, 64);
            part[i][r] = s;
        }

    __syncthreads();
    float* lout = (float*)smem;   // [128 rows][4 wn] partials
    if ((lane & 15) == 0) {
        int g = lane >> 4;
#pragma unroll
        for (int i = 0; i < 4; ++i)
#pragma unroll
            for (int r = 0; r < 4; ++r) {
                int row = wm * 64 + i * 16 + g * 4 + r;
                lout[row * 4 + wn] = part[i][r];
            }
    }
    __syncthreads();
    if (t < 128) {
        float s = lout[t * 4 + 0] + lout[t * 4 + 1] + lout[t * 4 + 2] + lout[t * 4 + 3]
                + B2[km];
        int brow = mt * 128 + t;
        // out[b, e, o] with k = o*E + e  ->  flat b*512 + (k%8)*64 + (k/8)
        out[(size_t)brow * 512 + (km & 7) * 64 + (km >> 3)] = s;
    }
}

extern "C" void kernel_launch(void* const* d_in, const int* in_sizes, int n_in,
                              void* d_out, int out_size, void* d_ws, size_t ws_size,
                              hipStream_t stream) {
    const float* X  = (const float*)d_in[0];
    const float* W1 = (const float*)d_in[1];
    const float* B1 = (const float*)d_in[2];
    const float* W2 = (const float*)d_in[3];
    const float* B2 = (const float*)d_in[4];
    float* out = (float*)d_out;

    ens_mlp_kernel<<<dim3(4096), dim3(512), 2 * LDS_BUF, stream>>>(X, W1, B1, W2, B2, out);
}

// Round 2
// 541.540 us; speedup vs baseline: 1.0052x; 1.0052x over previous
//
#include <hip/hip_runtime.h>
#include <hip/hip_bf16.h>

typedef __attribute__((ext_vector_type(8))) short short8;
typedef __attribute__((ext_vector_type(4))) float f32x4;
typedef __attribute__((ext_vector_type(4))) int i32x4;

#define LDS_BUF 40960      // bytes per buffer half: A(8KB) + B(32KB)
#define A_OFF 0
#define B_OFF 8192

// Grid: 4096 blocks = 512 MLPs x 8 m-tiles. Block: 512 threads (8 waves, 2M x 4N).
// Per block: computes h-pre[128 x 512] for one MLP k via bf16 MFMA, then fused
// relu + dot(W2) + b2 epilogue -> out[128 rows, k].
__global__ __launch_bounds__(512, 2)
void ens_mlp_kernel(const float* __restrict__ X,
                    const float* __restrict__ W1,
                    const float* __restrict__ B1,
                    const float* __restrict__ W2,
                    const float* __restrict__ B2,
                    float* __restrict__ out)
{
    extern __shared__ char smem[];
    const int t    = threadIdx.x;
    const int lane = t & 63;
    const int wv   = t >> 6;
    const int wm   = wv >> 2;   // 0..1  (M wave index)
    const int wn   = wv & 3;    // 0..3  (N wave index)

    // XCD-aware decode: 8 m-blocks of the same k land adjacent on one XCD.
    const int bb  = blockIdx.x;
    const int xcd = bb & 7;
    const int j   = bb >> 3;
    const int km  = xcd * 64 + (j >> 3);  // MLP index 0..511
    const int mt  = j & 7;                // m-tile 0..7

    const float* __restrict__ W1k = W1 + (size_t)km * (512 * 512);
    const float* __restrict__ Xm  = X + (size_t)mt * 128 * 512;

    f32x4 acc[4][8];
#pragma unroll
    for (int i = 0; i < 4; ++i)
#pragma unroll
        for (int p = 0; p < 8; ++p)
            acc[i][p] = (f32x4)0.0f;

    f32x4 sl[5][2];   // staged fp32 (8 floats per task)

    // Staging tasks (5 per thread per K-step):
    //  it<4 : W1 rows — id = it*512+t -> row=id>>2 (0..511), chunk c=id&3 (8 k's)
    //  it==4: X rows  — row=t>>2 (0..127), c=t&3
    // LDS dest is fragment-order: granule (c<<4)|(row&15) inside frag row>>4.
    auto stage_load = [&](int ks) {
#pragma unroll
        for (int it = 0; it < 5; ++it) {
            const float* src;
            if (it < 4) {
                int id  = it * 512 + t;
                int row = id >> 2, c = id & 3;
                src = W1k + row * 512 + ks * 32 + c * 8;
            } else {
                int row = t >> 2, c = t & 3;
                src = Xm + row * 512 + ks * 32 + c * 8;
            }
            sl[it][0] = *(const f32x4*)src;
            sl[it][1] = *(const f32x4*)(src + 4);
        }
    };

    auto stage_write = [&](int buf) {
        char* base = smem + buf * LDS_BUF;
#pragma unroll
        for (int it = 0; it < 5; ++it) {
            char* dst;
            if (it < 4) {
                int id  = it * 512 + t;
                int row = id >> 2, c = id & 3;
                dst = base + B_OFF + ((row >> 4) << 10) + (((c << 4) | (row & 15)) << 4);
            } else {
                int row = t >> 2, c = t & 3;
                dst = base + A_OFF + ((row >> 4) << 10) + (((c << 4) | (row & 15)) << 4);
            }
            union { __hip_bfloat162 h[4]; i32x4 v; } u;
            u.h[0] = __float22bfloat162_rn(make_float2(sl[it][0][0], sl[it][0][1]));
            u.h[1] = __float22bfloat162_rn(make_float2(sl[it][0][2], sl[it][0][3]));
            u.h[2] = __float22bfloat162_rn(make_float2(sl[it][1][0], sl[it][1][1]));
            u.h[3] = __float22bfloat162_rn(make_float2(sl[it][1][2], sl[it][1][3]));
            *(i32x4*)dst = u.v;
        }
    };

    // Fragment reads are linear (base + frag*1024 + lane*16): conflict-free.
    auto compute = [&](int buf) {
        const char* base = smem + buf * LDS_BUF;
        short8 av[4];
        short8 bv[8];
#pragma unroll
        for (int i = 0; i < 4; ++i)
            av[i] = *(const short8*)(base + A_OFF + ((wm * 4 + i) << 10) + (lane << 4));
#pragma unroll
        for (int p = 0; p < 8; ++p)
            bv[p] = *(const short8*)(base + B_OFF + ((wn * 8 + p) << 10) + (lane << 4));
#pragma unroll
        for (int i = 0; i < 4; ++i)
#pragma unroll
            for (int p = 0; p < 8; ++p)
                acc[i][p] = __builtin_amdgcn_mfma_f32_16x16x32_bf16(av[i], bv[p], acc[i][p], 0, 0, 0);
    };

    stage_load(0);
    stage_write(0);
    __syncthreads();

#pragma unroll 2
    for (int ks = 0; ks < 16; ++ks) {
        if (ks < 15) stage_load(ks + 1);      // issue global loads early (T14)
        compute(ks & 1);                      // ds_read + MFMA under load latency
        if (ks < 15) stage_write((ks + 1) & 1); // cvt + ds_write to other buffer
        __syncthreads();
    }

    // ---- fused epilogue: out[b, km] = sum_n relu(h + b1[n]) * w2[n] + b2 ----
    float b1v[8], w2v[8];
    const int nc = lane & 15;
#pragma unroll
    for (int p = 0; p < 8; ++p) {
        int n = wn * 128 + p * 16 + nc;
        b1v[p] = B1[km * 512 + n];
        w2v[p] = W2[km * 512 + n];
    }

    float part[4][4];
#pragma unroll
    for (int i = 0; i < 4; ++i)
#pragma unroll
        for (int r = 0; r < 4; ++r) {
            float s = 0.f;
#pragma unroll
            for (int p = 0; p < 8; ++p) {
                float h = acc[i][p][r] + b1v[p];
                h = h > 0.f ? h : 0.f;
                s += h * w2v[p];
            }
            // reduce over the 16 lanes that hold different n columns
#pragma unroll
            for (int d = 1; d < 16; d <<= 1)
                s += __shfl_xor(s, d, 64);
            part[i][r] = s;
        }

    __syncthreads();
    float* lout = (float*)smem;   // [128 rows][4 wn] partials
    if ((lane & 15) == 0) {
        int g = lane >> 4;
#pragma unroll
        for (int i = 0; i < 4; ++i)
#pragma unroll
            for (int r = 0; r < 4; ++r) {
                int row = wm * 64 + i * 16 + g * 4 + r;
                lout[row * 4 + wn] = part[i][r];
            }
    }
    __syncthreads();
    if (t < 128) {
        float s = lout[t * 4 + 0] + lout[t * 4 + 1] + lout[t * 4 + 2] + lout[t * 4 + 3]
                + B2[km];
        int brow = mt * 128 + t;
        // out[b, e, o] with k = o*E + e  ->  flat b*512 + (k%8)*64 + (k/8)
        out[(size_t)brow * 512 + (km & 7) * 64 + (km >> 3)] = s;
    }
}

extern "C" void kernel_launch(void* const* d_in, const int* in_sizes, int n_in,
                              void* d_out, int out_size, void* d_ws, size_t ws_size,
                              hipStream_t stream) {
    const float* X  = (const float*)d_in[0];
    const float* W1 = (const float*)d_in[1];
    const float* B1 = (const float*)d_in[2];
    const float* W2 = (const float*)d_in[3];
    const float* B2 = (const float*)d_in[4];
    float* out = (float*)d_out;

    ens_mlp_kernel<<<dim3(4096), dim3(512), 2 * LDS_BUF, stream>>>(X, W1, B1, W2, B2, out);
}